// Round 2
// 515.267 us; speedup vs baseline: 1.0066x; 1.0066x over previous
//
#include <hip/hip_runtime.h>
#include <cmath>

#define GH 384
#define GW 384
#define GN 32
#define C4 4            // float4 groups per pixel (16 channels)
#define RAD 6
#define KS 13
#define TW 32           // tile width (pixels)
#define TH 16           // tile height (output rows)
#define LROWS (TH + 2*RAD)   // 28 intermediate rows
#define PXH 8           // phase-1: pixels per horizontal strip task
#define PYV 4           // phase-2: output rows per thread (512 thr -> 4 each)
#define NTHREADS 512

struct Wt13 { float w[KS]; };

typedef float v4f __attribute__((ext_vector_type(4)));  // native vec for nontemporal store

// LDS layout: flat float4[LROWS*TW*C4], logical (lrow, col, c4).
// XOR bit2 (the col&1 position -> bank bit 4) with lrow parity so phase-1's
// per-p stores (col&1 == p&1 fixed) spread over all 32 banks instead of 16.
// Phase-2 reads are lrow-uniform per instruction -> permutation only, still
// a contiguous 1024B wave access -> conflict-free.
__device__ __forceinline__ int lidx(int r, int col, int c4) {
    int i = (r * TW + col) * C4 + c4;
    return i ^ ((r & 1) << 2);
}

__global__ __launch_bounds__(NTHREADS, 4)
void gauss13_kernel(const float4* __restrict__ x, float4* __restrict__ y, Wt13 wt) {
    __shared__ float4 lds4[LROWS * TW * C4];   // 57344 B -> 2 blocks/CU, 16 waves/CU

    // ---- bijective XCD swizzle: nwg = 12*24*32 = 9216, 9216 % 8 == 0 ----
    // Blocks with the same (orig % 8) land on the same XCD; give each XCD a
    // contiguous run of tiles so x/y halo neighbors share that XCD's L2.
    const int nwgx = GW / TW;          // 12
    const int nwgy = GH / TH;          // 24
    const int lin  = blockIdx.x + nwgx * (blockIdx.y + nwgy * blockIdx.z);
    const int per  = (nwgx * nwgy * GN) >> 3;    // 1152
    const int swz  = (lin & 7) * per + (lin >> 3);
    const int bx   = swz % nwgx;
    const int by   = (swz / nwgx) % nwgy;
    const int bz   = swz / (nwgx * nwgy);

    const int tid = threadIdx.x;
    const int w0 = bx * TW;
    const int h0 = by * TH;
    const int n  = bz;

    // ---------- phase 1: horizontal blur -> LDS ----------
    // task = (c4, colg, lrow); one task per thread (448 active of 512).
    {
        const int c4   = tid & 3;
        const int colg = (tid >> 2) & 3;        // 4 col-groups of 8
        const int lrow = tid >> 4;              // 0..31, skip >= 28
        if (lrow < LROWS) {
            const int gr = h0 - RAD + lrow;     // global row (may be OOB -> zeros)
            float4 ld[PXH + 2*RAD];
            if (gr >= 0 && gr < GH) {
                const float4* rowp = x + (size_t)(n * GH + gr) * GW * C4 + c4;
                #pragma unroll
                for (int k = 0; k < PXH + 2*RAD; ++k) {
                    const int gw = w0 + colg * PXH - RAD + k;
                    ld[k] = (gw >= 0 && gw < GW) ? rowp[(size_t)gw * C4]
                                                 : make_float4(0.f, 0.f, 0.f, 0.f);
                }
            } else {
                #pragma unroll
                for (int k = 0; k < PXH + 2*RAD; ++k)
                    ld[k] = make_float4(0.f, 0.f, 0.f, 0.f);
            }
            #pragma unroll
            for (int p = 0; p < PXH; ++p) {
                float sx = 0.f, sy = 0.f, sz = 0.f, sw = 0.f;
                #pragma unroll
                for (int k = 0; k < KS; ++k) {
                    const float g = wt.w[k];
                    sx += ld[p + k].x * g;
                    sy += ld[p + k].y * g;
                    sz += ld[p + k].z * g;
                    sw += ld[p + k].w * g;
                }
                lds4[lidx(lrow, colg * PXH + p, c4)] = make_float4(sx, sy, sz, sw);
            }
        }
    }
    __syncthreads();

    // ---------- phase 2: vertical blur from LDS -> global ----------
    // thread = (c4, col, row-chunk of 4); 16 ds_read_b128 -> 4 outputs.
    {
        const int c4  = tid & 3;
        const int col = (tid >> 2) & 31;
        const int r0  = (tid >> 7) * PYV;       // 0,4,8,12
        float4 acc[PYV];
        #pragma unroll
        for (int i = 0; i < PYV; ++i) acc[i] = make_float4(0.f, 0.f, 0.f, 0.f);
        #pragma unroll
        for (int t = 0; t < PYV + 2*RAD; ++t) { // 16 taps
            const float4 v = lds4[lidx(r0 + t, col, c4)];
            #pragma unroll
            for (int i = 0; i < PYV; ++i) {
                const int k = t - i;            // weight index, compile-time resolved
                if (k >= 0 && k < KS) {
                    const float g = wt.w[k];
                    acc[i].x += v.x * g;
                    acc[i].y += v.y * g;
                    acc[i].z += v.z * g;
                    acc[i].w += v.w * g;
                }
            }
        }
        float4* outp = y + ((size_t)(n * GH + h0 + r0) * GW + (w0 + col)) * C4 + c4;
        #pragma unroll
        for (int i = 0; i < PYV; ++i) {
            v4f v; v.x = acc[i].x; v.y = acc[i].y; v.z = acc[i].z; v.w = acc[i].w;
            __builtin_nontemporal_store(v, reinterpret_cast<v4f*>(outp + (size_t)i * GW * C4));
        }
    }
}

extern "C" void kernel_launch(void* const* d_in, const int* in_sizes, int n_in,
                              void* d_out, int out_size, void* d_ws, size_t ws_size,
                              hipStream_t stream) {
    const float4* x = (const float4*)d_in[0];
    float4* y = (float4*)d_out;

    // separable 1D weights: g/sum(g) per dim (outer(k,k)/sum == outer(g/s, g/s))
    Wt13 wt;
    double g[KS], s = 0.0;
    for (int i = 0; i < KS; ++i) { double d = i - 6.0; g[i] = exp(-(d * d) / 8.0); s += g[i]; }
    for (int i = 0; i < KS; ++i) wt.w[i] = (float)(g[i] / s);

    dim3 grid(GW / TW, GH / TH, GN);   // (12, 24, 32)
    gauss13_kernel<<<grid, NTHREADS, 0, stream>>>(x, y, wt);
}